// Round 8
// baseline (704.049 us; speedup 1.0000x reference)
//
#include <hip/hip_runtime.h>

// RopelessMLA on MI355X (gfx950).
// B=2 S=2048 D=1024 H=16 L=512 DH=64.
// scores = q @ (AK @ c_kv^T) = q @ k_abs^T with k_abs = c_kv @ AK^T.
// Attention = causal MHA (DH=64), fixed-max softmax => t-split + inline combine
// (split-K semaphore: last-finishing chunk block reduces the partials).

typedef __attribute__((ext_vector_type(4))) float f32x4;
typedef __attribute__((ext_vector_type(8))) unsigned short u16x8;
typedef __attribute__((ext_vector_type(4))) unsigned short u16x4;
typedef __attribute__((ext_vector_type(8))) __bf16 bf16x8;

__device__ __forceinline__ unsigned short f2bf(float f) {
  unsigned int u = __builtin_bit_cast(unsigned int, f);
  u += 0x7FFFu + ((u >> 16) & 1u);   // RNE; inputs finite
  return (unsigned short)(u >> 16);
}
__device__ __forceinline__ unsigned short f2bf_rz(float f) {  // truncate (P only)
  return (unsigned short)(__builtin_bit_cast(unsigned int, f) >> 16);
}
__device__ __forceinline__ float bf2f(unsigned short u) {
  return __builtin_bit_cast(float, (unsigned int)u << 16);
}

__device__ __forceinline__ f32x4 mfma16(u16x8 a, u16x8 b, f32x4 c) {
  return __builtin_amdgcn_mfma_f32_16x16x32_bf16(
      __builtin_bit_cast(bf16x8, a), __builtin_bit_cast(bf16x8, b), c, 0, 0, 0);
}

__device__ __forceinline__ void gload_lds16(const void* g, void* l) {
  __builtin_amdgcn_global_load_lds(
      (const __attribute__((address_space(1))) unsigned int*)g,
      (__attribute__((address_space(3))) unsigned int*)l, 16, 0, 0);
}

// ------- fused f32 -> bf16 converts (5 tensors) + W_uk transpose + counter zero ---
__global__ __launch_bounds__(256)
void fused_cvt(const float* __restrict__ x, unsigned short* __restrict__ xb,
               const float* __restrict__ wq, unsigned short* __restrict__ wqb,
               const float* __restrict__ wdkv, unsigned short* __restrict__ wdkvb,
               const float* __restrict__ wuv, unsigned short* __restrict__ wuvb,
               const float* __restrict__ wo, unsigned short* __restrict__ wob,
               const float* __restrict__ wuk, unsigned short* __restrict__ wukT,
               int* __restrict__ cnt) {
  __shared__ float t[64][65];
  if (blockIdx.x < 4) {                        // zero 1024 semaphores (for mla_attn7)
    cnt[blockIdx.x * 256 + threadIdx.x] = 0;
  }
  if (blockIdx.x >= 2048) {
    int bid = blockIdx.x - 2048;           // 0..127
    int c0 = (bid & 7) * 64;               // col block in [0,512)
    int r0 = (bid >> 3) * 64;              // row block in [0,1024)
    int lr = threadIdx.x >> 4, lc = (threadIdx.x & 15) * 4;
#pragma unroll
    for (int i = 0; i < 4; i++) {
      int row = lr + i * 16;
      float4 v = *(const float4*)(wuk + (size_t)(r0 + row) * 512 + c0 + lc);
      t[row][lc] = v.x; t[row][lc + 1] = v.y; t[row][lc + 2] = v.z; t[row][lc + 3] = v.w;
    }
    __syncthreads();
#pragma unroll
    for (int i = 0; i < 4; i++) {
      int oc = lr + i * 16;
      u16x4 o;
      o[0] = f2bf(t[lc + 0][oc]); o[1] = f2bf(t[lc + 1][oc]);
      o[2] = f2bf(t[lc + 2][oc]); o[3] = f2bf(t[lc + 3][oc]);
      *(u16x4*)(wukT + (size_t)(c0 + oc) * 1024 + r0 + lc) = o;
    }
    return;
  }
  const int total = 1048576 + 262144 + 131072 + 131072 + 262144;
  for (int i = blockIdx.x * 256 + threadIdx.x; i < total; i += 2048 * 256) {
    const float* src; unsigned short* dst; int off;
    if (i < 1048576)      { src = x;    dst = xb;    off = i; }
    else if (i < 1310720) { src = wq;   dst = wqb;   off = i - 1048576; }
    else if (i < 1441792) { src = wdkv; dst = wdkvb; off = i - 1310720; }
    else if (i < 1572864) { src = wuv;  dst = wuvb;  off = i - 1441792; }
    else                  { src = wo;   dst = wob;   off = i - 1572864; }
    float4 v = ((const float4*)src)[off];
    u16x4 o;
    o[0] = f2bf(v.x); o[1] = f2bf(v.y); o[2] = f2bf(v.z); o[3] = f2bf(v.w);
    ((u16x4*)dst)[off] = o;
  }
}

// ---------------- GEMM-BT device body: C[M,N] = A[M,K] * B[N,K]^T -----------------
// BK=64, double-buffered LDS, prefetch-before-compute, one barrier / K-step.
// XOR chunk swizzle (chunk ^ (row&7)) for conflict-free b128 LDS reads.
// MODE 0: bf16 C1. MODE 1: f32 C1. MODE 3: n0<1024 -> bf16 C1; else C2^T (ld 4096).
template <int MODE, int IM, int JF>
__device__ __forceinline__
void gemm_dev(int bx, int by,
              const unsigned short* __restrict__ A, const unsigned short* __restrict__ B,
              void* __restrict__ C1, void* __restrict__ C2,
              int K, int lda, int ldb, int ldc,
              unsigned short* sA, unsigned short* sB) {
  constexpr int BM = IM * 32, BN = JF * 32;
  const int tid = threadIdx.x;
  const int w = tid >> 6, ln = tid & 63;
  const int m0 = by * BM, n0 = bx * BN;
  const int wm = (w >> 1) * (IM * 16), wn = (w & 1) * (JF * 16);
  const int c16 = ln & 15, g = ln >> 4;
  f32x4 zero = {0.f, 0.f, 0.f, 0.f};
  f32x4 acc[IM][JF];
#pragma unroll
  for (int i = 0; i < IM; i++)
#pragma unroll
    for (int j = 0; j < JF; j++) acc[i][j] = zero;

#define STAGE_G(kt, bf)                                                         \
  {                                                                             \
    _Pragma("unroll") for (int l = 0; l < BM / 32; l++) {                       \
      int c = l * 256 + tid;                                                    \
      int row = c >> 3, pc = c & 7;                                             \
      gload_lds16(A + (size_t)(m0 + row) * lda + (kt) + ((pc ^ (row & 7)) << 3),\
                  (char*)(sA + (bf) * (BM * 64)) + (l * 256 + w * 64) * 16);    \
    }                                                                           \
    _Pragma("unroll") for (int l = 0; l < BN / 32; l++) {                       \
      int c = l * 256 + tid;                                                    \
      int row = c >> 3, pc = c & 7;                                             \
      gload_lds16(B + (size_t)(n0 + row) * ldb + (kt) + ((pc ^ (row & 7)) << 3),\
                  (char*)(sB + (bf) * (BN * 64)) + (l * 256 + w * 64) * 16);    \
    }                                                                           \
  }

  STAGE_G(0, 0);
  __syncthreads();
  int bf = 0;
  for (int kt = 0; kt < K; kt += 64) {
    if (kt + 64 < K) STAGE_G(kt + 64, bf ^ 1);
    u16x8 af[IM][2], bfr[JF][2];
#pragma unroll
    for (int i = 0; i < IM; i++) {
      int ra = wm + i * 16 + c16;
#pragma unroll
      for (int kk = 0; kk < 2; kk++)
        af[i][kk] = *(const u16x8*)((const char*)(sA + bf * (BM * 64)) + ra * 128 +
                                    ((((kk << 2) + g) ^ (ra & 7)) << 4));
    }
#pragma unroll
    for (int j = 0; j < JF; j++) {
      int rb = wn + j * 16 + c16;
#pragma unroll
      for (int kk = 0; kk < 2; kk++)
        bfr[j][kk] = *(const u16x8*)((const char*)(sB + bf * (BN * 64)) + rb * 128 +
                                     ((((kk << 2) + g) ^ (rb & 7)) << 4));
    }
#pragma unroll
    for (int kk = 0; kk < 2; kk++)
#pragma unroll
      for (int i = 0; i < IM; i++)
#pragma unroll
        for (int j = 0; j < JF; j++)
          acc[i][j] = mfma16(af[i][kk], bfr[j][kk], acc[i][j]);
    __syncthreads();
    bf ^= 1;
  }
#undef STAGE_G
  const int row0 = m0 + wm + g * 4;
  const int col0 = n0 + wn + c16;
  if (MODE == 1) {
    float* C = (float*)C1;
#pragma unroll
    for (int i = 0; i < IM; i++)
#pragma unroll
      for (int j = 0; j < JF; j++)
#pragma unroll
        for (int r = 0; r < 4; r++)
          C[(size_t)(row0 + i * 16 + r) * ldc + col0 + j * 16] = acc[i][j][r];
  } else if (MODE == 0) {
    unsigned short* C = (unsigned short*)C1;
#pragma unroll
    for (int i = 0; i < IM; i++)
#pragma unroll
      for (int j = 0; j < JF; j++)
#pragma unroll
        for (int r = 0; r < 4; r++)
          C[(size_t)(row0 + i * 16 + r) * ldc + col0 + j * 16] = f2bf(acc[i][j][r]);
  } else {  // MODE 3
    if (n0 < 1024) {
      unsigned short* C = (unsigned short*)C1;
#pragma unroll
      for (int i = 0; i < IM; i++)
#pragma unroll
        for (int j = 0; j < JF; j++)
#pragma unroll
          for (int r = 0; r < 4; r++)
            C[(size_t)(row0 + i * 16 + r) * ldc + col0 + j * 16] = f2bf(acc[i][j][r]);
    } else {
      unsigned short* C = (unsigned short*)C2;
#pragma unroll
      for (int i = 0; i < IM; i++)
#pragma unroll
        for (int j = 0; j < JF; j++) {
          u16x4 t4;
#pragma unroll
          for (int r = 0; r < 4; r++) t4[r] = f2bf(acc[i][j][r]);
          *(u16x4*)(C + (size_t)(col0 + j * 16 - 1024) * 4096 + row0 + i * 16) = t4;
        }
    }
  }
}

template <int MODE, int IM, int JF, int MINW>
__global__ __launch_bounds__(256, MINW)
void gemm_bt(const unsigned short* __restrict__ A, const unsigned short* __restrict__ B,
             void* __restrict__ C1, void* __restrict__ C2,
             int K, int lda, int ldb, int ldc) {
  __shared__ __align__(16) unsigned short sA[2 * IM * 32 * 64];
  __shared__ __align__(16) unsigned short sB[2 * JF * 32 * 64];
  gemm_dev<MODE, IM, JF>(blockIdx.x, blockIdx.y, A, B, C1, C2, K, lda, ldb, ldc,
                         sA, sB);
}

// ---------------- LayerNorm (blocks 0..1023) + AK GEMM (blocks 1024..1279) --------
// LN: rows of 512, c_f32 -> (f32 out, bf16 out).
// AK[hd][l] = sum_m Wq[hd][m] WukT[l][m]  (M=1024, N=512, K=1024, 32x64 tile).
__global__ __launch_bounds__(256, 4)
void lnak(const float* __restrict__ cin, const float* __restrict__ gamma,
          const float* __restrict__ beta, float* __restrict__ of32,
          unsigned short* __restrict__ obf,
          const unsigned short* __restrict__ wqb,
          const unsigned short* __restrict__ wukT,
          unsigned short* __restrict__ akt) {
  __shared__ __align__(16) unsigned short sh[2 * 32 * 64 + 2 * 64 * 64];
  if (blockIdx.x >= 1024) {
    int b2 = blockIdx.x - 1024;
    gemm_dev<0, 1, 2>(b2 & 7, b2 >> 3, wqb, wukT, akt, nullptr,
                      1024, 1024, 1024, 512, sh, sh + 2 * 32 * 64);
    return;
  }
  int row = blockIdx.x * 4 + (threadIdx.x >> 6);
  int ln = threadIdx.x & 63;
  const float* r = cin + (size_t)row * 512 + ln * 8;
  float4 a = *(const float4*)r;
  float4 b = *(const float4*)(r + 4);
  float xv[8] = {a.x, a.y, a.z, a.w, b.x, b.y, b.z, b.w};
  float s = 0.f, q = 0.f;
#pragma unroll
  for (int j = 0; j < 8; j++) { s += xv[j]; q += xv[j] * xv[j]; }
#pragma unroll
  for (int m = 1; m < 64; m <<= 1) { s += __shfl_xor(s, m); q += __shfl_xor(q, m); }
  float mu = s * (1.f / 512.f);
  float var = q * (1.f / 512.f) - mu * mu;
  float rs = rsqrtf(var + 1e-5f);
  float gm[8], bt[8];
  *(float4*)&gm[0] = *(const float4*)(gamma + ln * 8);
  *(float4*)&gm[4] = *(const float4*)(gamma + ln * 8 + 4);
  *(float4*)&bt[0] = *(const float4*)(beta + ln * 8);
  *(float4*)&bt[4] = *(const float4*)(beta + ln * 8 + 4);
  float o[8];
#pragma unroll
  for (int j = 0; j < 8; j++) o[j] = (xv[j] - mu) * rs * gm[j] + bt[j];
  float4 o0 = {o[0], o[1], o[2], o[3]}, o1 = {o[4], o[5], o[6], o[7]};
  *(float4*)(of32 + (size_t)row * 512 + ln * 8) = o0;
  *(float4*)(of32 + (size_t)row * 512 + ln * 8 + 4) = o1;
  u16x8 ob;
#pragma unroll
  for (int j = 0; j < 8; j++) ob[j] = f2bf(o[j]);
  *(u16x8*)(obf + (size_t)row * 512 + ln * 8) = ob;
}

// ---------------- Flash attention, t-split + inline combine ----------------------
// grid (80 chunks, 32 b*h), 256 thr = 4 waves x 16 q -> 64 q rows per qb.
// Chunk = up to 8 t-tiles of 64. Chunks per qb = qb/8+1. LDS 37888+ -> 4 blocks/CU.
// Each block writes unnormalized partials; last finisher per (bh,qb) combines.
__global__ __launch_bounds__(256, 4)
void mla_attn7(const unsigned short* __restrict__ kabs,  // [4096][1024] (t, h*64+d)
               const unsigned short* __restrict__ xq,    // [4096][1024] Q = x (bf16)
               const unsigned short* __restrict__ vT,    // [1024][4096] (h*64+d, t)
               unsigned short* __restrict__ Opart,       // [32][80][64][64] bf16
               float* __restrict__ Lpart,                // [32][80][64] f32
               int* __restrict__ cnt,                    // [32][32] semaphores
               unsigned short* __restrict__ ctx) {       // [4096][1024]
  __shared__ __align__(16) unsigned short sK[2][64 * 64];   // [t][d] chunk swz ^(t&7)
  __shared__ __align__(16) unsigned short sVT[2][64 * 64];  // [d][t] chunk swz ^(d&7)
  __shared__ __align__(16) unsigned short sP[4][16 * 40];   // per-wave [q][32t] pad 40
  __shared__ int sLast;
  const int tid = threadIdx.x, w = tid >> 6, ln = tid & 63;
  const int g = ln >> 4, c16 = ln & 15;
  const int bh = blockIdx.y;
  const int b = bh >> 4, h = bh & 15;
  // decode (qb, chunk) from blockIdx.x: qb/8+1 chunks per qb
  int cid = blockIdx.x, qb, ch;
  if (cid < 8)       { qb = cid;                 ch = 0; }
  else if (cid < 24) { qb = 8 + ((cid - 8) >> 1);  ch = (cid - 8) & 1; }
  else if (cid < 48) { qb = 16 + (cid - 24) / 3;   ch = (cid - 24) % 3; }
  else               { qb = 24 + ((cid - 48) >> 2); ch = (cid - 48) & 3; }
  const int ncq = (qb >> 3) + 1;
  const int ts = ch * 8;
  const int te = min(ts + 8, qb + 1);
  const int q0 = qb * 64;
  const int qw = q0 + w * 16;           // wave's first q row
  const size_t rowb = (size_t)b * 2048;

  u16x8 qf[2];
  {
    const unsigned short* qp = xq + (rowb + qw + c16) * 1024 + h * 64 + g * 8;
    qf[0] = *(const u16x8*)(qp);
    qf[1] = *(const u16x8*)(qp + 32);
  }
  f32x4 zero = {0.f, 0.f, 0.f, 0.f};
  f32x4 o[4] = {zero, zero, zero, zero};
  float lsum[4] = {0.f, 0.f, 0.f, 0.f};
  const float SC = 0.18033688011112042f;  // (1/8) * log2(e)
  const float M0 = 8.f;
  unsigned short* Pw = &sP[w][0];
  const unsigned short* kb_g = kabs + rowb * 1024 + h * 64;
  const unsigned short* vb_g = vT + (size_t)(h * 64) * 4096 + rowb;

#define STAGE_A(tt, bfi)                                                       \
  {                                                                            \
    int t0s = (tt) * 64;                                                       \
    _Pragma("unroll") for (int l = 0; l < 2; l++) {                            \
      int c = l * 256 + tid;                                                   \
      int row = c >> 3, pc = c & 7;                                            \
      gload_lds16(kb_g + (size_t)(t0s + row) * 1024 + ((pc ^ (row & 7)) << 3), \
                  (char*)&sK[bfi][0] + (l * 256 + w * 64) * 16);               \
    }                                                                          \
    _Pragma("unroll") for (int l = 0; l < 2; l++) {                            \
      int c = l * 256 + tid;                                                   \
      int row = c >> 3, pc = c & 7;                                            \
      gload_lds16(vb_g + (size_t)row * 4096 + t0s + ((pc ^ (row & 7)) << 3),   \
                  (char*)&sVT[bfi][0] + (l * 256 + w * 64) * 16);              \
    }                                                                          \
  }

  STAGE_A(ts, 0);
  __syncthreads();
  int bf = 0;
  for (int tt = ts; tt < te; tt++) {
    const int t0 = tt * 64;
    if (tt + 1 < te) STAGE_A(tt + 1, bf ^ 1);
    // S = Q K^T  (4 nt-tiles of 16 t, reduction 64)
    f32x4 s[4];
#pragma unroll
    for (int nt = 0; nt < 4; nt++) {
      int t = nt * 16 + c16;
      int sw = t & 7;
      const char* kb = (const char*)&sK[bf][0] + t * 128;
      f32x4 a = zero;
      a = mfma16(qf[0], *(const u16x8*)(kb + ((g ^ sw) << 4)), a);
      a = mfma16(qf[1], *(const u16x8*)(kb + (((4 + g) ^ sw) << 4)), a);
      s[nt] = a;
    }
    // fixed-max softmax: p = exp2(s*SC - M0); masked -> 0
    if (t0 + 63 <= qw) {
#pragma unroll
      for (int nt = 0; nt < 4; nt++)
#pragma unroll
        for (int r = 0; r < 4; r++) {
          float p = exp2f(s[nt][r] * SC - M0);
          lsum[r] += p;
          s[nt][r] = p;
        }
    } else {
#pragma unroll
      for (int nt = 0; nt < 4; nt++) {
        int tcol = t0 + nt * 16 + c16;
#pragma unroll
        for (int r = 0; r < 4; r++) {
          float p = (tcol <= qw + g * 4 + r) ? exp2f(s[nt][r] * SC - M0) : 0.f;
          lsum[r] += p;
          s[nt][r] = p;
        }
      }
    }
    // PV in two 32-t half passes through small per-wave sP (no barrier needed)
#pragma unroll
    for (int half = 0; half < 2; half++) {
#pragma unroll
      for (int ntl = 0; ntl < 2; ntl++)
#pragma unroll
        for (int r = 0; r < 4; r++)
          Pw[(g * 4 + r) * 40 + ntl * 16 + c16] = f2bf_rz(s[half * 2 + ntl][r]);
      u16x8 pa = *(const u16x8*)((const char*)Pw + c16 * 80 + g * 16);
#pragma unroll
      for (int dt = 0; dt < 4; dt++) {
        int d = dt * 16 + c16;
        const char* vb = (const char*)&sVT[bf][0] + d * 128 +
                         ((((half << 2) + g) ^ (d & 7)) << 4);
        o[dt] = mfma16(pa, *(const u16x8*)vb, o[dt]);
      }
    }
    __syncthreads();
    bf ^= 1;
  }
#undef STAGE_A
  // write unnormalized partials
  unsigned short* op = Opart + ((size_t)bh * 80 + cid) * 4096;
  float* lp = Lpart + ((size_t)bh * 80 + cid) * 64;
#pragma unroll
  for (int r = 0; r < 4; r++) {
    float t = lsum[r];
    t += __shfl_xor(t, 1); t += __shfl_xor(t, 2);
    t += __shfl_xor(t, 4); t += __shfl_xor(t, 8);
    int ql = w * 16 + g * 4 + r;
    if (c16 == 0) lp[ql] = t;
#pragma unroll
    for (int dt = 0; dt < 4; dt++)
      op[ql * 64 + dt * 16 + c16] = f2bf(o[dt][r]);
  }
  // ---- split-K semaphore: last finisher for (bh,qb) combines the partials ----
  __threadfence();            // device-scope release of our partials
  __syncthreads();
  if (tid == 0) {
    int old = atomicAdd(&cnt[bh * 32 + qb], 1);
    sLast = (old == ncq - 1);
  }
  __syncthreads();
  if (!sLast) return;
  __threadfence();            // device-scope acquire before reading others' partials
  const int cid0 = cid - ch;
  const int q = tid >> 2;
  const int d0 = (tid & 3) * 16;
  float acc[16];
#pragma unroll
  for (int j = 0; j < 16; j++) acc[j] = 0.f;
  float lacc = 0.f;
  for (int c = 0; c < ncq; c++) {
    size_t base = (size_t)bh * 80 + cid0 + c;
    lacc += Lpart[base * 64 + q];
    const unsigned short* op2 = Opart + base * 4096 + q * 64 + d0;
    u16x8 v0 = *(const u16x8*)(op2);
    u16x8 v1 = *(const u16x8*)(op2 + 8);
#pragma unroll
    for (int j = 0; j < 8; j++) { acc[j] += bf2f(v0[j]); acc[8 + j] += bf2f(v1[j]); }
  }
  float inv = 1.f / lacc;
  u16x8 o0, o1;
#pragma unroll
  for (int j = 0; j < 8; j++) {
    o0[j] = f2bf(acc[j] * inv);
    o1[j] = f2bf(acc[8 + j] * inv);
  }
  unsigned short* cp = ctx + ((size_t)b * 2048 + qb * 64 + q) * 1024 + h * 64 + d0;
  *(u16x8*)(cp) = o0;
  *(u16x8*)(cp + 8) = o1;
}

// ---------------- launch ----------------------------------------------------------
extern "C" void kernel_launch(void* const* d_in, const int* in_sizes, int n_in,
                              void* d_out, int out_size, void* d_ws, size_t ws_size,
                              hipStream_t stream) {
  const float* x    = (const float*)d_in[0];
  const float* Wq   = (const float*)d_in[1];
  const float* Wdkv = (const float*)d_in[2];
  const float* Wuk  = (const float*)d_in[3];
  const float* Wuv  = (const float*)d_in[4];
  const float* Wo   = (const float*)d_in[5];
  const float* gam  = (const float*)d_in[6];
  const float* bet  = (const float*)d_in[7];
  float* out_f = (float*)d_out;                       // [4096][1024]
  float* ckv_f = out_f + (size_t)4096 * 1024;         // [4096][512]

  char* ws = (char*)d_ws;
  unsigned short* xb     = (unsigned short*)(ws);              // 8 MB  [4096][1024]
  unsigned short* wq_b   = (unsigned short*)(ws + 8388608);    // 2 MB  [1024][1024]
  unsigned short* wdkv_b = (unsigned short*)(ws + 10485760);   // 1 MB  [512][1024]
  unsigned short* wukT_b = (unsigned short*)(ws + 11534336);   // 1 MB  [512][1024]
  unsigned short* akt_b  = (unsigned short*)(ws + 12582912);   // 1 MB  [1024][512]
  unsigned short* wuv_b  = (unsigned short*)(ws + 13631488);   // 1 MB  [1024][512]  (contiguous after akt -> B_cat)
  unsigned short* wo_b   = (unsigned short*)(ws + 14680064);   // 2 MB  [1024][1024]
  unsigned short* ckv_b  = (unsigned short*)(ws + 16777216);   // 4 MB  [4096][512]
  float*          c_f    = (float*)(ws + 20971520);            // 8 MB  [4096][512]
  unsigned short* kabs   = (unsigned short*)(ws + 29360128);   // 8 MB  [4096][1024]
  unsigned short* vT     = (unsigned short*)(ws + 37748736);   // 8 MB  [1024][4096]
  unsigned short* ctx_b  = (unsigned short*)(ws + 46137344);   // 8 MB  [4096][1024]
  unsigned short* Opart  = (unsigned short*)(ws + 54525952);   // 21 MB [32][80][64][64]
  float*          Lpart  = (float*)(ws + 75497472);            // 0.66MB [32][80][64]
  int*            cnt    = (int*)(ws + 76152832);              // 4 KB  [32][32]

  // L1: converts + W_uk transpose + semaphore zeroing
  fused_cvt<<<2176, 256, 0, stream>>>(x, xb, Wq, wq_b, Wdkv, wdkv_b,
                                      Wuv, wuv_b, Wo, wo_b, Wuk, wukT_b, cnt);
  // L2: c = x @ W_dkv^T  (f32 out)  [4096][512]
  gemm_bt<1, 2, 2, 4><<<dim3(8, 64), 256, 0, stream>>>(xb, wdkv_b, c_f, nullptr,
                                                       1024, 1024, 1024, 512);
  // L3: LayerNorm (1024 blocks) + AK GEMM (256 blocks)
  lnak<<<1280, 256, 0, stream>>>(c_f, gam, bet, ckv_f, ckv_b, wq_b, wukT_b, akt_b);
  // L4: [k_abs | v] = c_kv @ [AK; W_uv]^T  -> kabs [4096][1024], vT [1024][4096]
  gemm_bt<3, 4, 4, 2><<<dim3(16, 32), 256, 0, stream>>>(ckv_b, akt_b, kabs, vT,
                                                        512, 512, 512, 1024);
  // L5: flash attention t-split + inline combine -> ctx
  mla_attn7<<<dim3(80, 32), 256, 0, stream>>>(kabs, xb, vT, Opart, Lpart, cnt, ctx_b);
  // L6: out = ctx @ W_o^T  (f32 out)
  gemm_bt<1, 2, 4, 3><<<dim3(8, 64), 256, 0, stream>>>(ctx_b, wo_b, out_f, nullptr,
                                                       1024, 1024, 1024, 1024);
}

// Round 9
// 195.668 us; speedup vs baseline: 3.5982x; 3.5982x over previous
//
#include <hip/hip_runtime.h>

// RopelessMLA on MI355X (gfx950).
// B=2 S=2048 D=1024 H=16 L=512 DH=64.
// scores = q @ (AK @ c_kv^T) = q @ k_abs^T with k_abs = c_kv @ AK^T.
// Attention = causal MHA (DH=64), fixed-max softmax => t-split + separate combine
// kernel (device-scope fences proved catastrophic on non-coherent per-XCD L2s).

typedef __attribute__((ext_vector_type(4))) float f32x4;
typedef __attribute__((ext_vector_type(8))) unsigned short u16x8;
typedef __attribute__((ext_vector_type(4))) unsigned short u16x4;
typedef __attribute__((ext_vector_type(8))) __bf16 bf16x8;

__device__ __forceinline__ unsigned short f2bf(float f) {
  unsigned int u = __builtin_bit_cast(unsigned int, f);
  u += 0x7FFFu + ((u >> 16) & 1u);   // RNE; inputs finite
  return (unsigned short)(u >> 16);
}
__device__ __forceinline__ unsigned short f2bf_rz(float f) {  // truncate (P only)
  return (unsigned short)(__builtin_bit_cast(unsigned int, f) >> 16);
}
__device__ __forceinline__ float bf2f(unsigned short u) {
  return __builtin_bit_cast(float, (unsigned int)u << 16);
}

__device__ __forceinline__ f32x4 mfma16(u16x8 a, u16x8 b, f32x4 c) {
  return __builtin_amdgcn_mfma_f32_16x16x32_bf16(
      __builtin_bit_cast(bf16x8, a), __builtin_bit_cast(bf16x8, b), c, 0, 0, 0);
}

__device__ __forceinline__ void gload_lds16(const void* g, void* l) {
  __builtin_amdgcn_global_load_lds(
      (const __attribute__((address_space(1))) unsigned int*)g,
      (__attribute__((address_space(3))) unsigned int*)l, 16, 0, 0);
}

// ------- fused f32 -> bf16 converts (5 tensors) + W_uk transpose ------------------
__global__ __launch_bounds__(256)
void fused_cvt(const float* __restrict__ x, unsigned short* __restrict__ xb,
               const float* __restrict__ wq, unsigned short* __restrict__ wqb,
               const float* __restrict__ wdkv, unsigned short* __restrict__ wdkvb,
               const float* __restrict__ wuv, unsigned short* __restrict__ wuvb,
               const float* __restrict__ wo, unsigned short* __restrict__ wob,
               const float* __restrict__ wuk, unsigned short* __restrict__ wukT) {
  __shared__ float t[64][65];
  if (blockIdx.x >= 2048) {
    int bid = blockIdx.x - 2048;           // 0..127
    int c0 = (bid & 7) * 64;               // col block in [0,512)
    int r0 = (bid >> 3) * 64;              // row block in [0,1024)
    int lr = threadIdx.x >> 4, lc = (threadIdx.x & 15) * 4;
#pragma unroll
    for (int i = 0; i < 4; i++) {
      int row = lr + i * 16;
      float4 v = *(const float4*)(wuk + (size_t)(r0 + row) * 512 + c0 + lc);
      t[row][lc] = v.x; t[row][lc + 1] = v.y; t[row][lc + 2] = v.z; t[row][lc + 3] = v.w;
    }
    __syncthreads();
#pragma unroll
    for (int i = 0; i < 4; i++) {
      int oc = lr + i * 16;
      u16x4 o;
      o[0] = f2bf(t[lc + 0][oc]); o[1] = f2bf(t[lc + 1][oc]);
      o[2] = f2bf(t[lc + 2][oc]); o[3] = f2bf(t[lc + 3][oc]);
      *(u16x4*)(wukT + (size_t)(c0 + oc) * 1024 + r0 + lc) = o;
    }
    return;
  }
  const int total = 1048576 + 262144 + 131072 + 131072 + 262144;
  for (int i = blockIdx.x * 256 + threadIdx.x; i < total; i += 2048 * 256) {
    const float* src; unsigned short* dst; int off;
    if (i < 1048576)      { src = x;    dst = xb;    off = i; }
    else if (i < 1310720) { src = wq;   dst = wqb;   off = i - 1048576; }
    else if (i < 1441792) { src = wdkv; dst = wdkvb; off = i - 1310720; }
    else if (i < 1572864) { src = wuv;  dst = wuvb;  off = i - 1441792; }
    else                  { src = wo;   dst = wob;   off = i - 1572864; }
    float4 v = ((const float4*)src)[off];
    u16x4 o;
    o[0] = f2bf(v.x); o[1] = f2bf(v.y); o[2] = f2bf(v.z); o[3] = f2bf(v.w);
    ((u16x4*)dst)[off] = o;
  }
}

// ---------------- GEMM-BT device body: C[M,N] = A[M,K] * B[N,K]^T -----------------
// BK=64, double-buffered LDS, prefetch-before-compute, one barrier / K-step.
// XOR chunk swizzle (chunk ^ (row&7)) for conflict-free b128 LDS reads.
// MODE 0: bf16 C1. MODE 1: f32 C1. MODE 3: n0<1024 -> bf16 C1; else C2^T (ld 4096).
template <int MODE, int IM, int JF>
__device__ __forceinline__
void gemm_dev(int bx, int by,
              const unsigned short* __restrict__ A, const unsigned short* __restrict__ B,
              void* __restrict__ C1, void* __restrict__ C2,
              int K, int lda, int ldb, int ldc,
              unsigned short* sA, unsigned short* sB) {
  constexpr int BM = IM * 32, BN = JF * 32;
  const int tid = threadIdx.x;
  const int w = tid >> 6, ln = tid & 63;
  const int m0 = by * BM, n0 = bx * BN;
  const int wm = (w >> 1) * (IM * 16), wn = (w & 1) * (JF * 16);
  const int c16 = ln & 15, g = ln >> 4;
  f32x4 zero = {0.f, 0.f, 0.f, 0.f};
  f32x4 acc[IM][JF];
#pragma unroll
  for (int i = 0; i < IM; i++)
#pragma unroll
    for (int j = 0; j < JF; j++) acc[i][j] = zero;

#define STAGE_G(kt, bf)                                                         \
  {                                                                             \
    _Pragma("unroll") for (int l = 0; l < BM / 32; l++) {                       \
      int c = l * 256 + tid;                                                    \
      int row = c >> 3, pc = c & 7;                                             \
      gload_lds16(A + (size_t)(m0 + row) * lda + (kt) + ((pc ^ (row & 7)) << 3),\
                  (char*)(sA + (bf) * (BM * 64)) + (l * 256 + w * 64) * 16);    \
    }                                                                           \
    _Pragma("unroll") for (int l = 0; l < BN / 32; l++) {                       \
      int c = l * 256 + tid;                                                    \
      int row = c >> 3, pc = c & 7;                                             \
      gload_lds16(B + (size_t)(n0 + row) * ldb + (kt) + ((pc ^ (row & 7)) << 3),\
                  (char*)(sB + (bf) * (BN * 64)) + (l * 256 + w * 64) * 16);    \
    }                                                                           \
  }

  STAGE_G(0, 0);
  __syncthreads();
  int bf = 0;
  for (int kt = 0; kt < K; kt += 64) {
    if (kt + 64 < K) STAGE_G(kt + 64, bf ^ 1);
    u16x8 af[IM][2], bfr[JF][2];
#pragma unroll
    for (int i = 0; i < IM; i++) {
      int ra = wm + i * 16 + c16;
#pragma unroll
      for (int kk = 0; kk < 2; kk++)
        af[i][kk] = *(const u16x8*)((const char*)(sA + bf * (BM * 64)) + ra * 128 +
                                    ((((kk << 2) + g) ^ (ra & 7)) << 4));
    }
#pragma unroll
    for (int j = 0; j < JF; j++) {
      int rb = wn + j * 16 + c16;
#pragma unroll
      for (int kk = 0; kk < 2; kk++)
        bfr[j][kk] = *(const u16x8*)((const char*)(sB + bf * (BN * 64)) + rb * 128 +
                                     ((((kk << 2) + g) ^ (rb & 7)) << 4));
    }
#pragma unroll
    for (int kk = 0; kk < 2; kk++)
#pragma unroll
      for (int i = 0; i < IM; i++)
#pragma unroll
        for (int j = 0; j < JF; j++)
          acc[i][j] = mfma16(af[i][kk], bfr[j][kk], acc[i][j]);
    __syncthreads();
    bf ^= 1;
  }
#undef STAGE_G
  const int row0 = m0 + wm + g * 4;
  const int col0 = n0 + wn + c16;
  if (MODE == 1) {
    float* C = (float*)C1;
#pragma unroll
    for (int i = 0; i < IM; i++)
#pragma unroll
      for (int j = 0; j < JF; j++)
#pragma unroll
        for (int r = 0; r < 4; r++)
          C[(size_t)(row0 + i * 16 + r) * ldc + col0 + j * 16] = acc[i][j][r];
  } else if (MODE == 0) {
    unsigned short* C = (unsigned short*)C1;
#pragma unroll
    for (int i = 0; i < IM; i++)
#pragma unroll
      for (int j = 0; j < JF; j++)
#pragma unroll
        for (int r = 0; r < 4; r++)
          C[(size_t)(row0 + i * 16 + r) * ldc + col0 + j * 16] = f2bf(acc[i][j][r]);
  } else {  // MODE 3
    if (n0 < 1024) {
      unsigned short* C = (unsigned short*)C1;
#pragma unroll
      for (int i = 0; i < IM; i++)
#pragma unroll
        for (int j = 0; j < JF; j++)
#pragma unroll
          for (int r = 0; r < 4; r++)
            C[(size_t)(row0 + i * 16 + r) * ldc + col0 + j * 16] = f2bf(acc[i][j][r]);
    } else {
      unsigned short* C = (unsigned short*)C2;
#pragma unroll
      for (int i = 0; i < IM; i++)
#pragma unroll
        for (int j = 0; j < JF; j++) {
          u16x4 t4;
#pragma unroll
          for (int r = 0; r < 4; r++) t4[r] = f2bf(acc[i][j][r]);
          *(u16x4*)(C + (size_t)(col0 + j * 16 - 1024) * 4096 + row0 + i * 16) = t4;
        }
    }
  }
}

template <int MODE, int IM, int JF, int MINW>
__global__ __launch_bounds__(256, MINW)
void gemm_bt(const unsigned short* __restrict__ A, const unsigned short* __restrict__ B,
             void* __restrict__ C1, void* __restrict__ C2,
             int K, int lda, int ldb, int ldc) {
  __shared__ __align__(16) unsigned short sA[2 * IM * 32 * 64];
  __shared__ __align__(16) unsigned short sB[2 * JF * 32 * 64];
  gemm_dev<MODE, IM, JF>(blockIdx.x, blockIdx.y, A, B, C1, C2, K, lda, ldb, ldc,
                         sA, sB);
}

// ---------------- LayerNorm (blocks 0..1023) + AK GEMM (blocks 1024..1279) --------
__global__ __launch_bounds__(256, 4)
void lnak(const float* __restrict__ cin, const float* __restrict__ gamma,
          const float* __restrict__ beta, float* __restrict__ of32,
          unsigned short* __restrict__ obf,
          const unsigned short* __restrict__ wqb,
          const unsigned short* __restrict__ wukT,
          unsigned short* __restrict__ akt) {
  __shared__ __align__(16) unsigned short sh[2 * 32 * 64 + 2 * 64 * 64];
  if (blockIdx.x >= 1024) {
    int b2 = blockIdx.x - 1024;
    gemm_dev<0, 1, 2>(b2 & 7, b2 >> 3, wqb, wukT, akt, nullptr,
                      1024, 1024, 1024, 512, sh, sh + 2 * 32 * 64);
    return;
  }
  int row = blockIdx.x * 4 + (threadIdx.x >> 6);
  int ln = threadIdx.x & 63;
  const float* r = cin + (size_t)row * 512 + ln * 8;
  float4 a = *(const float4*)r;
  float4 b = *(const float4*)(r + 4);
  float xv[8] = {a.x, a.y, a.z, a.w, b.x, b.y, b.z, b.w};
  float s = 0.f, q = 0.f;
#pragma unroll
  for (int j = 0; j < 8; j++) { s += xv[j]; q += xv[j] * xv[j]; }
#pragma unroll
  for (int m = 1; m < 64; m <<= 1) { s += __shfl_xor(s, m); q += __shfl_xor(q, m); }
  float mu = s * (1.f / 512.f);
  float var = q * (1.f / 512.f) - mu * mu;
  float rs = rsqrtf(var + 1e-5f);
  float gm[8], bt[8];
  *(float4*)&gm[0] = *(const float4*)(gamma + ln * 8);
  *(float4*)&gm[4] = *(const float4*)(gamma + ln * 8 + 4);
  *(float4*)&bt[0] = *(const float4*)(beta + ln * 8);
  *(float4*)&bt[4] = *(const float4*)(beta + ln * 8 + 4);
  float o[8];
#pragma unroll
  for (int j = 0; j < 8; j++) o[j] = (xv[j] - mu) * rs * gm[j] + bt[j];
  float4 o0 = {o[0], o[1], o[2], o[3]}, o1 = {o[4], o[5], o[6], o[7]};
  *(float4*)(of32 + (size_t)row * 512 + ln * 8) = o0;
  *(float4*)(of32 + (size_t)row * 512 + ln * 8 + 4) = o1;
  u16x8 ob;
#pragma unroll
  for (int j = 0; j < 8; j++) ob[j] = f2bf(o[j]);
  *(u16x8*)(obf + (size_t)row * 512 + ln * 8) = ob;
}

// ---------------- Flash attention, t-split, 8 waves/tile (DH=64, causal) ----------
// grid (40 chunks, 32 b*h), 512 thr = 8 waves x 16 q -> 128 q rows per qb2.
// Chunk = up to 8 t-tiles of 64. Chunks per qb2 = qb2/4+1 (40 total/bh).
// K/V staged once per tile, shared by 8 waves. LDS 42.25KB -> 3 blocks/CU
// (24 waves/CU). Emits UNNORMALIZED partial O (bf16) + partial lsum (f32).
__global__ __launch_bounds__(512, 3)
void mla_attn8(const unsigned short* __restrict__ kabs,  // [4096][1024] (t, h*64+d)
               const unsigned short* __restrict__ xq,    // [4096][1024] Q = x (bf16)
               const unsigned short* __restrict__ vT,    // [1024][4096] (h*64+d, t)
               unsigned short* __restrict__ Opart,       // [32][40][128][64] bf16
               float* __restrict__ Lpart) {              // [32][40][128] f32
  __shared__ __align__(16) unsigned short sK[2][64 * 64];   // [t][d] chunk swz ^(t&7)
  __shared__ __align__(16) unsigned short sVT[2][64 * 64];  // [d][t] chunk swz ^(d&7)
  __shared__ __align__(16) unsigned short sP[8][16 * 40];   // per-wave [q][32t] pad 40
  const int tid = threadIdx.x, w = tid >> 6, ln = tid & 63;
  const int g = ln >> 4, c16 = ln & 15;
  const int bh = blockIdx.y;
  const int b = bh >> 4, h = bh & 15;
  // decode (qb2, chunk): chunks per qb2 = qb2/4+1; starts [0,4,12,24]
  int cid = blockIdx.x, qb2, ch;
  if (cid < 4)       { qb2 = cid;                  ch = 0; }
  else if (cid < 12) { qb2 = 4 + ((cid - 4) >> 1);   ch = (cid - 4) & 1; }
  else if (cid < 24) { qb2 = 8 + (cid - 12) / 3;     ch = (cid - 12) % 3; }
  else               { qb2 = 12 + ((cid - 24) >> 2); ch = (cid - 24) & 3; }
  const int ts = ch * 8;
  const int te = min(ts + 8, 2 * qb2 + 2);
  const int q0 = qb2 * 128;
  const int qw = q0 + w * 16;           // wave's first q row
  const size_t rowb = (size_t)b * 2048;

  u16x8 qf[2];
  {
    const unsigned short* qp = xq + (rowb + qw + c16) * 1024 + h * 64 + g * 8;
    qf[0] = *(const u16x8*)(qp);
    qf[1] = *(const u16x8*)(qp + 32);
  }
  f32x4 zero = {0.f, 0.f, 0.f, 0.f};
  f32x4 o[4] = {zero, zero, zero, zero};
  float lsum[4] = {0.f, 0.f, 0.f, 0.f};
  const float SC = 0.18033688011112042f;  // (1/8) * log2(e)
  const float M0 = 8.f;
  unsigned short* Pw = &sP[w][0];
  const unsigned short* kb_g = kabs + rowb * 1024 + h * 64;
  const unsigned short* vb_g = vT + (size_t)(h * 64) * 4096 + rowb;
  const int srow = tid >> 3, spc = tid & 7;   // 512 thr: one 16B gload per tensor

#define STAGE_A(tt, bfi)                                                        \
  {                                                                             \
    int t0s = (tt) * 64;                                                        \
    gload_lds16(kb_g + (size_t)(t0s + srow) * 1024 + ((spc ^ (srow & 7)) << 3), \
                (char*)&sK[bfi][0] + (w << 10));                                \
    gload_lds16(vb_g + (size_t)srow * 4096 + t0s + ((spc ^ (srow & 7)) << 3),   \
                (char*)&sVT[bfi][0] + (w << 10));                               \
  }

  STAGE_A(ts, 0);
  __syncthreads();
  int bf = 0;
  for (int tt = ts; tt < te; tt++) {
    const int t0 = tt * 64;
    if (tt + 1 < te) STAGE_A(tt + 1, bf ^ 1);
    // S = Q K^T  (4 nt-tiles of 16 t, reduction 64)
    f32x4 s[4];
#pragma unroll
    for (int nt = 0; nt < 4; nt++) {
      int t = nt * 16 + c16;
      int sw = t & 7;
      const char* kb = (const char*)&sK[bf][0] + t * 128;
      f32x4 a = zero;
      a = mfma16(qf[0], *(const u16x8*)(kb + ((g ^ sw) << 4)), a);
      a = mfma16(qf[1], *(const u16x8*)(kb + (((4 + g) ^ sw) << 4)), a);
      s[nt] = a;
    }
    // fixed-max softmax: p = exp2(s*SC - M0); masked -> 0
    if (t0 + 63 <= qw) {
#pragma unroll
      for (int nt = 0; nt < 4; nt++)
#pragma unroll
        for (int r = 0; r < 4; r++) {
          float p = exp2f(s[nt][r] * SC - M0);
          lsum[r] += p;
          s[nt][r] = p;
        }
    } else {
#pragma unroll
      for (int nt = 0; nt < 4; nt++) {
        int tcol = t0 + nt * 16 + c16;
#pragma unroll
        for (int r = 0; r < 4; r++) {
          float p = (tcol <= qw + g * 4 + r) ? exp2f(s[nt][r] * SC - M0) : 0.f;
          lsum[r] += p;
          s[nt][r] = p;
        }
      }
    }
    // PV in two 32-t half passes through small per-wave sP (no barrier needed)
#pragma unroll
    for (int half = 0; half < 2; half++) {
#pragma unroll
      for (int ntl = 0; ntl < 2; ntl++)
#pragma unroll
        for (int r = 0; r < 4; r++)
          Pw[(g * 4 + r) * 40 + ntl * 16 + c16] = f2bf_rz(s[half * 2 + ntl][r]);
      u16x8 pa = *(const u16x8*)((const char*)Pw + c16 * 80 + g * 16);
#pragma unroll
      for (int dt = 0; dt < 4; dt++) {
        int d = dt * 16 + c16;
        const char* vb = (const char*)&sVT[bf][0] + d * 128 +
                         ((((half << 2) + g) ^ (d & 7)) << 4);
        o[dt] = mfma16(pa, *(const u16x8*)vb, o[dt]);
      }
    }
    __syncthreads();
    bf ^= 1;
  }
#undef STAGE_A
  // write unnormalized partials
  unsigned short* op = Opart + ((size_t)bh * 40 + cid) * 8192;
  float* lp = Lpart + ((size_t)bh * 40 + cid) * 128;
#pragma unroll
  for (int r = 0; r < 4; r++) {
    float t = lsum[r];
    t += __shfl_xor(t, 1); t += __shfl_xor(t, 2);
    t += __shfl_xor(t, 4); t += __shfl_xor(t, 8);
    int ql = w * 16 + g * 4 + r;
    if (c16 == 0) lp[ql] = t;
#pragma unroll
    for (int dt = 0; dt < 4; dt++)
      op[ql * 64 + dt * 16 + c16] = f2bf(o[dt][r]);
  }
}

// ---------------- combine partials -> ctx -----------------------------------------
// grid (16 qb2, 32 bh), 512 thr. thread: q = tid>>2 (0..127), d0 = (tid&3)*16.
__global__ __launch_bounds__(512)
void attn_combine(const unsigned short* __restrict__ Opart,
                  const float* __restrict__ Lpart,
                  unsigned short* __restrict__ ctx) {    // [4096][1024]
  const int qb2 = blockIdx.x, bh = blockIdx.y;
  const int b = bh >> 4, h = bh & 15;
  const int ncq = (qb2 >> 2) + 1;
  const int gg = qb2 >> 2;
  const int start = (gg == 0 ? 0 : (gg == 1 ? 4 : (gg == 2 ? 12 : 24)));
  const int cid0 = start + (qb2 & 3) * ncq;
  const int q = threadIdx.x >> 2;
  const int d0 = (threadIdx.x & 3) * 16;
  float acc[16];
#pragma unroll
  for (int j = 0; j < 16; j++) acc[j] = 0.f;
  float lacc = 0.f;
  for (int c = 0; c < ncq; c++) {
    size_t base = (size_t)bh * 40 + cid0 + c;
    lacc += Lpart[base * 128 + q];
    const unsigned short* op = Opart + base * 8192 + q * 64 + d0;
    u16x8 v0 = *(const u16x8*)(op);
    u16x8 v1 = *(const u16x8*)(op + 8);
#pragma unroll
    for (int j = 0; j < 8; j++) { acc[j] += bf2f(v0[j]); acc[8 + j] += bf2f(v1[j]); }
  }
  float inv = 1.f / lacc;
  u16x8 o0, o1;
#pragma unroll
  for (int j = 0; j < 8; j++) { o0[j] = f2bf(acc[j] * inv); o1[j] = f2bf(acc[8 + j] * inv); }
  unsigned short* cp = ctx + ((size_t)b * 2048 + qb2 * 128 + q) * 1024 + h * 64 + d0;
  *(u16x8*)(cp) = o0;
  *(u16x8*)(cp + 8) = o1;
}

// ---------------- launch ----------------------------------------------------------
extern "C" void kernel_launch(void* const* d_in, const int* in_sizes, int n_in,
                              void* d_out, int out_size, void* d_ws, size_t ws_size,
                              hipStream_t stream) {
  const float* x    = (const float*)d_in[0];
  const float* Wq   = (const float*)d_in[1];
  const float* Wdkv = (const float*)d_in[2];
  const float* Wuk  = (const float*)d_in[3];
  const float* Wuv  = (const float*)d_in[4];
  const float* Wo   = (const float*)d_in[5];
  const float* gam  = (const float*)d_in[6];
  const float* bet  = (const float*)d_in[7];
  float* out_f = (float*)d_out;                       // [4096][1024]
  float* ckv_f = out_f + (size_t)4096 * 1024;         // [4096][512]

  char* ws = (char*)d_ws;
  unsigned short* xb     = (unsigned short*)(ws);              // 8 MB  [4096][1024]
  unsigned short* wq_b   = (unsigned short*)(ws + 8388608);    // 2 MB  [1024][1024]
  unsigned short* wdkv_b = (unsigned short*)(ws + 10485760);   // 1 MB  [512][1024]
  unsigned short* wukT_b = (unsigned short*)(ws + 11534336);   // 1 MB  [512][1024]
  unsigned short* akt_b  = (unsigned short*)(ws + 12582912);   // 1 MB  [1024][512]
  unsigned short* wuv_b  = (unsigned short*)(ws + 13631488);   // 1 MB  [1024][512]  (contiguous after akt -> B_cat)
  unsigned short* wo_b   = (unsigned short*)(ws + 14680064);   // 2 MB  [1024][1024]
  unsigned short* ckv_b  = (unsigned short*)(ws + 16777216);   // 4 MB  [4096][512]
  float*          c_f    = (float*)(ws + 20971520);            // 8 MB  [4096][512]
  unsigned short* kabs   = (unsigned short*)(ws + 29360128);   // 8 MB  [4096][1024]
  unsigned short* vT     = (unsigned short*)(ws + 37748736);   // 8 MB  [1024][4096]
  unsigned short* ctx_b  = (unsigned short*)(ws + 46137344);   // 8 MB  [4096][1024]
  unsigned short* Opart  = (unsigned short*)(ws + 54525952);   // 20 MB [32][40][128][64]
  float*          Lpart  = (float*)(ws + 75497472);            // 0.66MB [32][40][128]

  // L1: converts + W_uk transpose
  fused_cvt<<<2176, 256, 0, stream>>>(x, xb, Wq, wq_b, Wdkv, wdkv_b,
                                      Wuv, wuv_b, Wo, wo_b, Wuk, wukT_b);
  // L2: c = x @ W_dkv^T  (f32 out)  [4096][512]
  gemm_bt<1, 2, 2, 4><<<dim3(8, 64), 256, 0, stream>>>(xb, wdkv_b, c_f, nullptr,
                                                       1024, 1024, 1024, 512);
  // L3: LayerNorm (1024 blocks) + AK GEMM (256 blocks)
  lnak<<<1280, 256, 0, stream>>>(c_f, gam, bet, ckv_f, ckv_b, wq_b, wukT_b, akt_b);
  // L4: [k_abs | v] = c_kv @ [AK; W_uv]^T  -> kabs [4096][1024], vT [1024][4096]
  gemm_bt<3, 4, 4, 2><<<dim3(16, 32), 256, 0, stream>>>(ckv_b, akt_b, kabs, vT,
                                                        512, 512, 512, 1024);
  // L5: flash attention t-split (8 waves/tile) -> partials
  mla_attn8<<<dim3(40, 32), 512, 0, stream>>>(kabs, xb, vT, Opart, Lpart);
  // L6: combine partials -> ctx
  attn_combine<<<dim3(16, 32), 512, 0, stream>>>(Opart, Lpart, ctx_b);
  // L7: out = ctx @ W_o^T  (f32 out)
  gemm_bt<1, 2, 4, 3><<<dim3(8, 64), 256, 0, stream>>>(ctx_b, wo_b, out_f, nullptr,
                                                       1024, 1024, 1024, 1024);
}